// Round 2
// baseline (433.990 us; speedup 1.0000x reference)
//
#include <hip/hip_runtime.h>
#include <hip/hip_fp16.h>

typedef _Float16 half8 __attribute__((ext_vector_type(8)));
typedef float f32x4 __attribute__((ext_vector_type(4)));

constexpr int M = 2048;    // B*S = 4*512
constexpr int N = 10240;   // DOUT
constexpr int K = 4096;    // DIN
constexpr int BM = 128, BN = 128, BK = 64;

// NOTE (harness dtype contract): fp16 is NOT a supported storage dtype.
// input_tensor / bias (fp16 in the reference) arrive as fp32 buffers holding
// fp16-exact values; output buffer is fp32 (fp16-rounded values expected).

__global__ __launch_bounds__(256, 2)
void qlinear_fp8_kernel(const float* __restrict__ A,    // [M, K] fp32 (fp16-valued)
                        const float* __restrict__ W,    // [N, K] fp32
                        const float* __restrict__ Wsc,  // [N]    fp32
                        const float* __restrict__ bias, // [N]    fp32 (fp16-valued)
                        float*       __restrict__ C)    // [M, N] fp32 out
{
    __shared__ _Float16 As[BM][BK];   // 16 KB
    __shared__ _Float16 Bs[BN][BK];   // 16 KB

    // XCD-bijective block swizzle (nwg=1280, 1280%8==0): 16 row-blocks sharing
    // one 128-col weight panel are consecutive within an XCD chunk.
    const int nwg  = (M / BM) * (N / BN);            // 1280
    const int orig = blockIdx.x;
    const int wgid = (orig & 7) * (nwg >> 3) + (orig >> 3);
    const int brow = wgid & (M / BM - 1);            // & 15
    const int bcol = wgid / (M / BM);
    const int m0 = brow * BM;
    const int n0 = bcol * BN;

    const int t    = threadIdx.x;
    const int lane = t & 63;
    const int wave = t >> 6;
    const int wr = (wave >> 1) * 64;   // wave's row offset in tile
    const int wc = (wave & 1) * 64;    // wave's col offset in tile
    const int fr = lane & 15;          // fragment row/col index
    const int fk = (lane >> 4) * 8;    // fragment k offset (8 contiguous halves)

    const int srow = t >> 3;           // staging row 0..31
    const int scol = (t & 7) * 8;      // staging k offset (8 elems)

    // Per-output-channel scales, pre-rounded to fp16 (ref: scale.astype(f16)).
    _Float16 hs[4];
#pragma unroll
    for (int p = 0; p < 4; ++p)
        hs[p] = (_Float16)Wsc[n0 + srow + p * 32];

    f32x4 acc[4][4];
#pragma unroll
    for (int i = 0; i < 4; ++i)
#pragma unroll
        for (int j = 0; j < 4; ++j)
            acc[i][j] = (f32x4){0.f, 0.f, 0.f, 0.f};

    for (int k0 = 0; k0 < K; k0 += BK) {
        __syncthreads();   // previous compute done before overwriting LDS

        // ---- stage A: fp32 (fp16-valued) -> fp16, 8 elems/thread/pass.
        // Cast is exact (values are fp16-representable).
#pragma unroll
        for (int c = 0; c < 4; ++c) {
            const int rl = c * 32 + srow;
            const float* asrc = A + (size_t)(m0 + rl) * K + (k0 + scol);
            const float4 a0 = ((const float4*)asrc)[0];
            const float4 a1 = ((const float4*)asrc)[1];
            half8 av;
            av[0] = (_Float16)a0.x; av[1] = (_Float16)a0.y;
            av[2] = (_Float16)a0.z; av[3] = (_Float16)a0.w;
            av[4] = (_Float16)a1.x; av[5] = (_Float16)a1.y;
            av[6] = (_Float16)a1.z; av[7] = (_Float16)a1.w;
            *(half8*)&As[rl][scol] = av;
        }

        // ---- stage B: fused dequant. (f16)w * (f16)scale, IEEE half RN ==
        // reference's weight.astype(f16) * scale.astype(f16).
#pragma unroll
        for (int p = 0; p < 4; ++p) {
            const int nl = srow + p * 32;
            const float* wsrc = W + (size_t)(n0 + nl) * K + (k0 + scol);
            const float4 w0 = ((const float4*)wsrc)[0];
            const float4 w1 = ((const float4*)wsrc)[1];
            half8 hv;
            hv[0] = (_Float16)w0.x * hs[p];
            hv[1] = (_Float16)w0.y * hs[p];
            hv[2] = (_Float16)w0.z * hs[p];
            hv[3] = (_Float16)w0.w * hs[p];
            hv[4] = (_Float16)w1.x * hs[p];
            hv[5] = (_Float16)w1.y * hs[p];
            hv[6] = (_Float16)w1.z * hs[p];
            hv[7] = (_Float16)w1.w * hs[p];
            *(half8*)&Bs[nl][scol] = hv;
        }

        __syncthreads();   // ds_writes drained before compute

        // ---- compute: 2 x (8 ds_read_b128 + 16 MFMA)
#pragma unroll
        for (int kk = 0; kk < BK; kk += 32) {
            half8 av[4], bv[4];
#pragma unroll
            for (int i = 0; i < 4; ++i)
                av[i] = *(const half8*)&As[wr + i * 16 + fr][kk + fk];
#pragma unroll
            for (int j = 0; j < 4; ++j)
                bv[j] = *(const half8*)&Bs[wc + j * 16 + fr][kk + fk];
#pragma unroll
            for (int i = 0; i < 4; ++i)
#pragma unroll
                for (int j = 0; j < 4; ++j)
                    acc[i][j] = __builtin_amdgcn_mfma_f32_16x16x32_f16(
                        av[i], bv[j], acc[i][j], 0, 0, 0);
        }
    }

    // ---- epilogue: C/D layout col = lane&15, row = (lane>>4)*4 + reg.
    // Round through fp16 (reference output dtype), store fp32.
#pragma unroll
    for (int i = 0; i < 4; ++i) {
        const int row = m0 + wr + i * 16 + (lane >> 4) * 4;
#pragma unroll
        for (int j = 0; j < 4; ++j) {
            const int col = n0 + wc + j * 16 + fr;
            const float bb = bias[col];
#pragma unroll
            for (int r = 0; r < 4; ++r)
                C[(size_t)(row + r) * N + col] =
                    (float)(_Float16)(acc[i][j][r] + bb);
        }
    }
}

extern "C" void kernel_launch(void* const* d_in, const int* in_sizes, int n_in,
                              void* d_out, int out_size, void* d_ws, size_t ws_size,
                              hipStream_t stream) {
    const float* A    = (const float*)d_in[0];  // input_tensor (fp16 values, fp32 storage)
    const float* W    = (const float*)d_in[1];  // weight fp32
    const float* Wsc  = (const float*)d_in[2];  // weight_scale fp32
    const float* bias = (const float*)d_in[3];  // bias (fp16 values, fp32 storage)
    float* C = (float*)d_out;

    const int nwg = (M / BM) * (N / BN);  // 1280
    qlinear_fp8_kernel<<<dim3(nwg), dim3(256), 0, stream>>>(A, W, Wsc, bias, C);
}

// Round 3
// 275.625 us; speedup vs baseline: 1.5746x; 1.5746x over previous
//
#include <hip/hip_runtime.h>
#include <hip/hip_fp16.h>

typedef _Float16 half8 __attribute__((ext_vector_type(8)));
typedef float f32x4 __attribute__((ext_vector_type(4)));

constexpr int M = 2048;    // B*S
constexpr int N = 10240;   // DOUT
constexpr int K = 4096;    // DIN
constexpr int BM = 128, BN = 128, BK = 64;

// ---------------------------------------------------------------------------
// Pre-pass 1: dequantize W (fp32) -> fp16 * fp16(scale) into workspace.
// Bit-identical to the reference: weight.astype(f16) * scale.astype(f16).
__global__ __launch_bounds__(256)
void dequant_w_kernel(const float* __restrict__ W, const float* __restrict__ Wsc,
                      _Float16* __restrict__ Wh) {
    const long total = (long)N * K / 8;
    for (long i = (long)blockIdx.x * blockDim.x + threadIdx.x; i < total;
         i += (long)gridDim.x * blockDim.x) {
        const long base = i * 8;
        const int row = (int)(base >> 12);           // / K
        const _Float16 s = (_Float16)Wsc[row];
        const float4 w0 = ((const float4*)(W + base))[0];
        const float4 w1 = ((const float4*)(W + base))[1];
        half8 h;
        h[0] = (_Float16)w0.x * s; h[1] = (_Float16)w0.y * s;
        h[2] = (_Float16)w0.z * s; h[3] = (_Float16)w0.w * s;
        h[4] = (_Float16)w1.x * s; h[5] = (_Float16)w1.y * s;
        h[6] = (_Float16)w1.z * s; h[7] = (_Float16)w1.w * s;
        *(half8*)(Wh + base) = h;
    }
}

// Pre-pass 2: A fp32 (fp16-valued) -> fp16 (exact).
__global__ __launch_bounds__(256)
void convert_a_kernel(const float* __restrict__ A, _Float16* __restrict__ Ah) {
    const long total = (long)M * K / 8;
    for (long i = (long)blockIdx.x * blockDim.x + threadIdx.x; i < total;
         i += (long)gridDim.x * blockDim.x) {
        const long base = i * 8;
        const float4 a0 = ((const float4*)(A + base))[0];
        const float4 a1 = ((const float4*)(A + base))[1];
        half8 h;
        h[0] = (_Float16)a0.x; h[1] = (_Float16)a0.y;
        h[2] = (_Float16)a0.z; h[3] = (_Float16)a0.w;
        h[4] = (_Float16)a1.x; h[5] = (_Float16)a1.y;
        h[6] = (_Float16)a1.z; h[7] = (_Float16)a1.w;
        *(half8*)(Ah + base) = h;
    }
}

// ---------------------------------------------------------------------------
// Main GEMM: pure fp16, m97 structure — global_load_lds width=16 for BOTH
// operands, 128x128 tile, BK=64, 4 waves, 4x4 16x16x32 fragments per wave.
__global__ __launch_bounds__(256, 2)
void qgemm_f16_kernel(const _Float16* __restrict__ A,  // [M,K] fp16 (ws)
                      const _Float16* __restrict__ W,  // [N,K] fp16 dequant (ws)
                      const float*    __restrict__ bias, // [N] fp32 (fp16-valued)
                      float*          __restrict__ C)  // [M,N] fp32 out
{
    __shared__ _Float16 As[BM][BK];   // 16 KB
    __shared__ _Float16 Bs[BN][BK];   // 16 KB

    // XCD-bijective swizzle (nwg=1280 % 8 == 0): the 16 row-blocks sharing a
    // 128-col weight panel are consecutive within one XCD chunk.
    const int nwg  = (M / BM) * (N / BN);            // 1280
    const int orig = blockIdx.x;
    const int wgid = (orig & 7) * (nwg >> 3) + (orig >> 3);
    const int brow = wgid & (M / BM - 1);
    const int bcol = wgid / (M / BM);
    const int m0 = brow * BM;
    const int n0 = bcol * BN;

    const int t    = threadIdx.x;
    const int lane = t & 63;
    const int wave = t >> 6;
    const int wr = (wave >> 1) * 64;
    const int wc = (wave & 1) * 64;
    const int fr = lane & 15;
    const int fk = (lane >> 4) * 8;

    const int srow = t >> 3;           // 0..31
    const int scol = (t & 7) * 8;

    f32x4 acc[4][4];
#pragma unroll
    for (int i = 0; i < 4; ++i)
#pragma unroll
        for (int j = 0; j < 4; ++j)
            acc[i][j] = (f32x4){0.f, 0.f, 0.f, 0.f};

    for (int k0 = 0; k0 < K; k0 += BK) {
        __syncthreads();   // LDS free before overwrite

        // stage A + B: 8 x global_load_lds dwordx4; LDS dest == t*16 bytes
        // within each 32-row slab (linear, matches wave-uniform + lane*16).
#pragma unroll
        for (int c = 0; c < 4; ++c) {
            const _Float16* ga = A + (size_t)(m0 + c * 32 + srow) * K + (k0 + scol);
            __builtin_amdgcn_global_load_lds(
                (const __attribute__((address_space(1))) void*)ga,
                (__attribute__((address_space(3))) void*)&As[c * 32 + srow][scol],
                16, 0, 0);
            const _Float16* gb = W + (size_t)(n0 + c * 32 + srow) * K + (k0 + scol);
            __builtin_amdgcn_global_load_lds(
                (const __attribute__((address_space(1))) void*)gb,
                (__attribute__((address_space(3))) void*)&Bs[c * 32 + srow][scol],
                16, 0, 0);
        }

        __syncthreads();   // drains vmcnt -> tiles visible

#pragma unroll
        for (int kk = 0; kk < BK; kk += 32) {
            half8 av[4], bv[4];
#pragma unroll
            for (int i = 0; i < 4; ++i)
                av[i] = *(const half8*)&As[wr + i * 16 + fr][kk + fk];
#pragma unroll
            for (int j = 0; j < 4; ++j)
                bv[j] = *(const half8*)&Bs[wc + j * 16 + fr][kk + fk];
#pragma unroll
            for (int i = 0; i < 4; ++i)
#pragma unroll
                for (int j = 0; j < 4; ++j)
                    acc[i][j] = __builtin_amdgcn_mfma_f32_16x16x32_f16(
                        av[i], bv[j], acc[i][j], 0, 0, 0);
        }
    }

    // epilogue: col = lane&15, row = (lane>>4)*4 + reg; round through fp16.
#pragma unroll
    for (int i = 0; i < 4; ++i) {
        const int row = m0 + wr + i * 16 + (lane >> 4) * 4;
#pragma unroll
        for (int j = 0; j < 4; ++j) {
            const int col = n0 + wc + j * 16 + fr;
            const float bb = bias[col];
#pragma unroll
            for (int r = 0; r < 4; ++r)
                C[(size_t)(row + r) * N + col] =
                    (float)(_Float16)(acc[i][j][r] + bb);
        }
    }
}

// ---------------------------------------------------------------------------
// Fallback: round-2 fused kernel (passing, 434 us) if ws too small.
__global__ __launch_bounds__(256, 2)
void qlinear_fused_kernel(const float* __restrict__ A, const float* __restrict__ W,
                          const float* __restrict__ Wsc, const float* __restrict__ bias,
                          float* __restrict__ C)
{
    __shared__ _Float16 As[BM][BK];
    __shared__ _Float16 Bs[BN][BK];

    const int nwg  = (M / BM) * (N / BN);
    const int orig = blockIdx.x;
    const int wgid = (orig & 7) * (nwg >> 3) + (orig >> 3);
    const int brow = wgid & (M / BM - 1);
    const int bcol = wgid / (M / BM);
    const int m0 = brow * BM;
    const int n0 = bcol * BN;

    const int t    = threadIdx.x;
    const int lane = t & 63;
    const int wave = t >> 6;
    const int wr = (wave >> 1) * 64;
    const int wc = (wave & 1) * 64;
    const int fr = lane & 15;
    const int fk = (lane >> 4) * 8;
    const int srow = t >> 3;
    const int scol = (t & 7) * 8;

    _Float16 hs[4];
#pragma unroll
    for (int p = 0; p < 4; ++p)
        hs[p] = (_Float16)Wsc[n0 + srow + p * 32];

    f32x4 acc[4][4];
#pragma unroll
    for (int i = 0; i < 4; ++i)
#pragma unroll
        for (int j = 0; j < 4; ++j)
            acc[i][j] = (f32x4){0.f, 0.f, 0.f, 0.f};

    for (int k0 = 0; k0 < K; k0 += BK) {
        __syncthreads();
#pragma unroll
        for (int c = 0; c < 4; ++c) {
            const int rl = c * 32 + srow;
            const float* asrc = A + (size_t)(m0 + rl) * K + (k0 + scol);
            const float4 a0 = ((const float4*)asrc)[0];
            const float4 a1 = ((const float4*)asrc)[1];
            half8 av;
            av[0] = (_Float16)a0.x; av[1] = (_Float16)a0.y;
            av[2] = (_Float16)a0.z; av[3] = (_Float16)a0.w;
            av[4] = (_Float16)a1.x; av[5] = (_Float16)a1.y;
            av[6] = (_Float16)a1.z; av[7] = (_Float16)a1.w;
            *(half8*)&As[rl][scol] = av;
        }
#pragma unroll
        for (int p = 0; p < 4; ++p) {
            const int nl = srow + p * 32;
            const float* wsrc = W + (size_t)(n0 + nl) * K + (k0 + scol);
            const float4 w0 = ((const float4*)wsrc)[0];
            const float4 w1 = ((const float4*)wsrc)[1];
            half8 hv;
            hv[0] = (_Float16)w0.x * hs[p]; hv[1] = (_Float16)w0.y * hs[p];
            hv[2] = (_Float16)w0.z * hs[p]; hv[3] = (_Float16)w0.w * hs[p];
            hv[4] = (_Float16)w1.x * hs[p]; hv[5] = (_Float16)w1.y * hs[p];
            hv[6] = (_Float16)w1.z * hs[p]; hv[7] = (_Float16)w1.w * hs[p];
            *(half8*)&Bs[nl][scol] = hv;
        }
        __syncthreads();
#pragma unroll
        for (int kk = 0; kk < BK; kk += 32) {
            half8 av[4], bv[4];
#pragma unroll
            for (int i = 0; i < 4; ++i)
                av[i] = *(const half8*)&As[wr + i * 16 + fr][kk + fk];
#pragma unroll
            for (int j = 0; j < 4; ++j)
                bv[j] = *(const half8*)&Bs[wc + j * 16 + fr][kk + fk];
#pragma unroll
            for (int i = 0; i < 4; ++i)
#pragma unroll
                for (int j = 0; j < 4; ++j)
                    acc[i][j] = __builtin_amdgcn_mfma_f32_16x16x32_f16(
                        av[i], bv[j], acc[i][j], 0, 0, 0);
        }
    }
#pragma unroll
    for (int i = 0; i < 4; ++i) {
        const int row = m0 + wr + i * 16 + (lane >> 4) * 4;
#pragma unroll
        for (int j = 0; j < 4; ++j) {
            const int col = n0 + wc + j * 16 + fr;
            const float bb = bias[col];
#pragma unroll
            for (int r = 0; r < 4; ++r)
                C[(size_t)(row + r) * N + col] =
                    (float)(_Float16)(acc[i][j][r] + bb);
        }
    }
}

extern "C" void kernel_launch(void* const* d_in, const int* in_sizes, int n_in,
                              void* d_out, int out_size, void* d_ws, size_t ws_size,
                              hipStream_t stream) {
    const float* A    = (const float*)d_in[0];
    const float* W    = (const float*)d_in[1];
    const float* Wsc  = (const float*)d_in[2];
    const float* bias = (const float*)d_in[3];
    float* C = (float*)d_out;

    const size_t a_bytes = (size_t)M * K * sizeof(_Float16);   // 16.78 MB
    const size_t w_bytes = (size_t)N * K * sizeof(_Float16);   // 83.89 MB
    const int nwg = (M / BM) * (N / BN);  // 1280

    if (ws_size >= a_bytes + w_bytes) {
        _Float16* Ah = (_Float16*)d_ws;
        _Float16* Wh = (_Float16*)((char*)d_ws + a_bytes);
        convert_a_kernel<<<dim3(1024), dim3(256), 0, stream>>>(A, Ah);
        dequant_w_kernel<<<dim3(2048), dim3(256), 0, stream>>>(W, Wsc, Wh);
        qgemm_f16_kernel<<<dim3(nwg), dim3(256), 0, stream>>>(Ah, Wh, bias, C);
    } else {
        qlinear_fused_kernel<<<dim3(nwg), dim3(256), 0, stream>>>(A, W, Wsc, bias, C);
    }
}